// Round 2
// baseline (1073.674 us; speedup 1.0000x reference)
//
#include <hip/hip_runtime.h>
#include <cmath>

#define TM 128
#define TN 128
#define TK 16
#define LDSW 132          // padded LDS row width (floats)
#define BAND 1e-4
#define FIXCAP 262144u

// ---------------------------------------------------------------------------
// Shared 128x128x16 fp32 tile mainloop, 256 threads, 8x8 micro-tile split as
// 2x2 blocks of 4x4.  Double-buffered LDS ping-pong: prefetch tile t+1 into
// registers during compute of tile t, ONE barrier per K-step (writes go to
// the other buffer, so no read/write hazard).  Accumulation order identical
// to the single-buffered version -> bitwise-same acc.
// ---------------------------------------------------------------------------
#define STAGE_STORE(B)                                                          \
        As[B][aq * 4 + 0][ar] = pa0.x; As[B][aq * 4 + 1][ar] = pa0.y;           \
        As[B][aq * 4 + 2][ar] = pa0.z; As[B][aq * 4 + 3][ar] = pa0.w;           \
        As[B][aq * 4 + 0][ar + 64] = pa1.x; As[B][aq * 4 + 1][ar + 64] = pa1.y; \
        As[B][aq * 4 + 2][ar + 64] = pa1.z; As[B][aq * 4 + 3][ar + 64] = pa1.w; \
        *(float4*)&Bs[B][bk][bn4] = pb0;                                        \
        *(float4*)&Bs[B][bk + 8][bn4] = pb1;

#define GEMM_MAINLOOP(Aptr, Wptr, Kdim, Ndim)                                   \
    __shared__ float As[2][TK][LDSW];                                           \
    __shared__ float Bs[2][TK][LDSW];                                           \
    const int tid = threadIdx.x;                                                \
    const int bm = blockIdx.x * TM;                                             \
    const int bn = blockIdx.y * TN;                                             \
    const int tx = tid & 15, ty = tid >> 4;                                     \
    const int ar = tid >> 2, aq = tid & 3;                                      \
    const int bk = tid >> 5, bn4 = (tid & 31) * 4;                              \
    float acc[2][2][4][4];                                                      \
    _Pragma("unroll") for (int a = 0; a < 2; ++a)                               \
    _Pragma("unroll") for (int b = 0; b < 2; ++b)                               \
    _Pragma("unroll") for (int i = 0; i < 4; ++i)                               \
    _Pragma("unroll") for (int j = 0; j < 4; ++j) acc[a][b][i][j] = 0.f;        \
    float4 pa0 = *(const float4*)((Aptr) + (size_t)(bm + ar) * (Kdim) + aq * 4);      \
    float4 pa1 = *(const float4*)((Aptr) + (size_t)(bm + ar + 64) * (Kdim) + aq * 4); \
    float4 pb0 = *(const float4*)((Wptr) + (size_t)bk * (Ndim) + bn + bn4);           \
    float4 pb1 = *(const float4*)((Wptr) + (size_t)(bk + 8) * (Ndim) + bn + bn4);     \
    STAGE_STORE(0)                                                              \
    __syncthreads();                                                            \
    int buf = 0;                                                                \
    for (int k0 = 0; k0 < (Kdim); k0 += TK) {                                   \
        const int nk = k0 + TK;                                                 \
        if (nk < (Kdim)) {                                                      \
            pa0 = *(const float4*)((Aptr) + (size_t)(bm + ar) * (Kdim) + nk + aq * 4);      \
            pa1 = *(const float4*)((Aptr) + (size_t)(bm + ar + 64) * (Kdim) + nk + aq * 4); \
            pb0 = *(const float4*)((Wptr) + (size_t)(nk + bk) * (Ndim) + bn + bn4);         \
            pb1 = *(const float4*)((Wptr) + (size_t)(nk + bk + 8) * (Ndim) + bn + bn4);     \
        }                                                                       \
        _Pragma("unroll") for (int k = 0; k < TK; ++k) {                        \
            float4 da0 = *(const float4*)&As[buf][k][ty * 4];                   \
            float4 da1 = *(const float4*)&As[buf][k][64 + ty * 4];              \
            float4 db0 = *(const float4*)&Bs[buf][k][tx * 4];                   \
            float4 db1 = *(const float4*)&Bs[buf][k][64 + tx * 4];              \
            const float* dap[2] = {&da0.x, &da1.x};                             \
            const float* dbp[2] = {&db0.x, &db1.x};                             \
            _Pragma("unroll") for (int a = 0; a < 2; ++a)                       \
            _Pragma("unroll") for (int b = 0; b < 2; ++b)                       \
            _Pragma("unroll") for (int i = 0; i < 4; ++i)                       \
            _Pragma("unroll") for (int j = 0; j < 4; ++j)                       \
                acc[a][b][i][j] = fmaf(dap[a][i], dbp[b][j], acc[a][b][i][j]);  \
        }                                                                       \
        if (nk < (Kdim)) {                                                      \
            const int nb = buf ^ 1;                                             \
            STAGE_STORE(nb)                                                     \
            __syncthreads();                                                    \
            buf = nb;                                                           \
        }                                                                       \
    }

// ---------------------------------------------------------------------------
// K1: h1 = relu(F @ Wg1 + b1), fp32.  F:[M,1024], Wg1:[1024,256], out:[M,256]
// ---------------------------------------------------------------------------
__global__ __launch_bounds__(256) void gemm1_f32(
    const float* __restrict__ A, const float* __restrict__ W,
    const float* __restrict__ bias, float* __restrict__ out, int M)
{
    const int K = 1024, N = 256;
    GEMM_MAINLOOP(A, W, K, N)
    #pragma unroll
    for (int a = 0; a < 2; ++a) {
        #pragma unroll
        for (int b = 0; b < 2; ++b) {
            const int col = bn + b * 64 + tx * 4;
            float4 bi = *(const float4*)(bias + col);
            #pragma unroll
            for (int i = 0; i < 4; ++i) {
                const int row = bm + a * 64 + ty * 4 + i;
                float4 o;
                o.x = fmaxf(acc[a][b][i][0] + bi.x, 0.f);
                o.y = fmaxf(acc[a][b][i][1] + bi.y, 0.f);
                o.z = fmaxf(acc[a][b][i][2] + bi.z, 0.f);
                o.w = fmaxf(acc[a][b][i][3] + bi.w, 0.f);
                *(float4*)(out + (size_t)row * N + col) = o;
            }
        }
    }
}

// ---------------------------------------------------------------------------
// K2: z2 = h1 @ Wg2 + b2; g = F * sigmoid(z2); comp = (g>0.3)?0:g.
// Epilogue in fp64 (matches the validated baseline bitwise: same fp32 acc,
// same fp64 sigmoid).  The |comp|<0.1 and |dyn|>thr decisions downstream are
// unprotected discrete boundaries, so comp must not be perturbed.
// Flags |g-0.3| < BAND for exact fp64 fixup.
// ---------------------------------------------------------------------------
__global__ __launch_bounds__(256) void gemm2_f32(
    const float* __restrict__ A, const float* __restrict__ W,
    const float* __restrict__ bias, const float* __restrict__ F,
    float* __restrict__ out, unsigned* __restrict__ counter,
    uint2* __restrict__ list, int M)
{
    const int K = 256, N = 1024;
    GEMM_MAINLOOP(A, W, K, N)
    #pragma unroll
    for (int a = 0; a < 2; ++a) {
        #pragma unroll
        for (int b = 0; b < 2; ++b) {
            const int col = bn + b * 64 + tx * 4;
            float4 bi = *(const float4*)(bias + col);
            const float* bip = &bi.x;
            #pragma unroll
            for (int i = 0; i < 4; ++i) {
                const int row = bm + a * 64 + ty * 4 + i;
                float4 fv = *(const float4*)(F + (size_t)row * N + col);
                const float* fvp = &fv.x;
                float4 o;
                float* op = &o.x;
                #pragma unroll
                for (int j = 0; j < 4; ++j) {
                    double z = (double)acc[a][b][i][j] + (double)bip[j];
                    double gw = 1.0 / (1.0 + exp(-z));
                    double g = (double)fvp[j] * gw;
                    if (fabs(g - 0.3) < BAND) {
                        unsigned idx = atomicAdd(counter, 1u);
                        if (idx < FIXCAP) list[idx] = make_uint2((unsigned)row, (unsigned)(col + j));
                    }
                    double c = (g > 0.3) ? 0.0 : g;
                    op[j] = (float)c;
                }
                *(float4*)(out + (size_t)row * N + col) = o;
            }
        }
    }
}

// ---------------------------------------------------------------------------
// fix1: exact fp64 recompute of comp for flagged (row,col) elements.
// ---------------------------------------------------------------------------
__global__ __launch_bounds__(256) void fix_exact(
    const float* __restrict__ F, const float* __restrict__ Wg1,
    const float* __restrict__ bg1, const float* __restrict__ Wg2,
    const float* __restrict__ bg2, const unsigned* __restrict__ counter,
    const uint2* __restrict__ list, float* __restrict__ out)
{
    __shared__ float Fs[1024];
    __shared__ double red[4];
    const int tid = threadIdx.x;
    unsigned cnt = *counter;
    if (cnt > FIXCAP) cnt = FIXCAP;

    for (unsigned e = blockIdx.x; e < cnt; e += gridDim.x) {
        const unsigned row = list[e].x, col = list[e].y;
        *(float4*)&Fs[tid * 4] = *(const float4*)(F + (size_t)row * 1024 + tid * 4);
        __syncthreads();
        double acc = 0.0;
        #pragma unroll 4
        for (int j = 0; j < 1024; ++j)
            acc += (double)Fs[j] * (double)Wg1[(size_t)j * 256 + tid];
        double h = acc + (double)bg1[tid];
        h = (h > 0.0) ? h : 0.0;
        double p = h * (double)Wg2[(size_t)tid * 1024 + col];
        #pragma unroll
        for (int o = 32; o > 0; o >>= 1) p += __shfl_down(p, o, 64);
        if ((tid & 63) == 0) red[tid >> 6] = p;
        __syncthreads();
        if (tid == 0) {
            double z2 = red[0] + red[1] + red[2] + red[3] + (double)bg2[col];
            double gw = 1.0 / (1.0 + exp(-z2));
            double g = (double)Fs[col] * gw;
            double c = (g > 0.3) ? 0.0 : g;
            out[(size_t)row * 1024 + col] = (float)c;
        }
        __syncthreads();
    }
}

// ---------------------------------------------------------------------------
// K3: per-row finalize (in-place on d_out).  One WAVE per row (64 lanes x 16
// elems), butterfly __shfl_xor reductions -> zero __syncthreads.  All math
// stays fp64 (reduction-order change vs baseline is ~1e-15 on mean/std).
// Block = 256 threads = 4 rows.
// ---------------------------------------------------------------------------
__global__ __launch_bounds__(256) void finalize_rows(
    float* __restrict__ C,
    const float* __restrict__ wr1, const float* __restrict__ br1,
    const float* __restrict__ wr2, const float* __restrict__ br2,
    const float* __restrict__ wm1, const float* __restrict__ bm1,
    const float* __restrict__ wm2, const float* __restrict__ bm2)
{
    const int D = 1024;
    const int tid = threadIdx.x;
    const int lane = tid & 63;
    const size_t row = (size_t)blockIdx.x * 4 + (tid >> 6);
    const size_t base = row * D;
    const int col0 = lane * 4;

    float4 c4[4];
    #pragma unroll
    for (int q = 0; q < 4; ++q)
        c4[q] = *(const float4*)(C + base + q * 256 + col0);

    double c[16];
    #pragma unroll
    for (int q = 0; q < 4; ++q) {
        c[q * 4 + 0] = (double)c4[q].x; c[q * 4 + 1] = (double)c4[q].y;
        c[q * 4 + 2] = (double)c4[q].z; c[q * 4 + 3] = (double)c4[q].w;
    }

    // current sparsity
    double cnt = 0.0;
    #pragma unroll
    for (int i = 0; i < 16; ++i) cnt += (fabs(c[i]) < 0.1) ? 1.0 : 0.0;
    #pragma unroll
    for (int o = 32; o > 0; o >>= 1) cnt += __shfl_xor(cnt, o, 64);
    double cur_sp = cnt / 1024.0;

    // sparsity_feedback hidden layer (uniform across lanes, computed redundantly)
    double hid[16];
    #pragma unroll
    for (int h = 0; h < 16; ++h) {
        double z = cur_sp * (double)wr1[h] + 0.1 * (double)wr1[16 + h] + (double)br1[h];
        hid[h] = (z > 0.0) ? z : 0.0;
    }

    // dyn = comp * sigmoid(hid @ wr2 + br2)
    double dyn[16];
    #pragma unroll
    for (int q = 0; q < 4; ++q) {
        const int cq = q * 256 + col0;
        float4 b4 = *(const float4*)(br2 + cq);
        double z[4] = {(double)b4.x, (double)b4.y, (double)b4.z, (double)b4.w};
        #pragma unroll
        for (int h = 0; h < 16; ++h) {
            float4 w4 = *(const float4*)(wr2 + (size_t)h * D + cq);
            z[0] += hid[h] * (double)w4.x;
            z[1] += hid[h] * (double)w4.y;
            z[2] += hid[h] * (double)w4.z;
            z[3] += hid[h] * (double)w4.w;
        }
        #pragma unroll
        for (int j = 0; j < 4; ++j) {
            double rw = 1.0 / (1.0 + exp(-z[j]));
            dyn[q * 4 + j] = c[q * 4 + j] * rw;
        }
    }

    // row stats: mean, std (ddof=1), max — all in-wave butterflies
    double s = 0.0, mx = -1e300;
    #pragma unroll
    for (int i = 0; i < 16; ++i) { s += dyn[i]; mx = fmax(mx, dyn[i]); }
    #pragma unroll
    for (int o = 32; o > 0; o >>= 1) s += __shfl_xor(s, o, 64);
    double mean = s / 1024.0;

    double sq = 0.0;
    #pragma unroll
    for (int i = 0; i < 16; ++i) { double d = dyn[i] - mean; sq += d * d; }
    #pragma unroll
    for (int o = 32; o > 0; o >>= 1) sq += __shfl_xor(sq, o, 64);
    double sd = sqrt(sq / 1023.0);

    #pragma unroll
    for (int o = 32; o > 0; o >>= 1) mx = fmax(mx, __shfl_xor(mx, o, 64));

    // adaptive threshold (uniform, computed redundantly per lane)
    double acc2 = (double)bm2[0];
    #pragma unroll
    for (int h = 0; h < 16; ++h) {
        double hz = mean * (double)wm1[h] + sd * (double)wm1[16 + h]
                  + mx * (double)wm1[32 + h] + (double)bm1[h];
        hz = (hz > 0.0) ? hz : 0.0;
        acc2 += hz * (double)wm2[h];
    }
    double thr = 1.0 / (1.0 + exp(-acc2));

    #pragma unroll
    for (int q = 0; q < 4; ++q) {
        float4 o4;
        o4.x = (float)((fabs(dyn[q * 4 + 0]) > thr) ? dyn[q * 4 + 0] : 0.0);
        o4.y = (float)((fabs(dyn[q * 4 + 1]) > thr) ? dyn[q * 4 + 1] : 0.0);
        o4.z = (float)((fabs(dyn[q * 4 + 2]) > thr) ? dyn[q * 4 + 2] : 0.0);
        o4.w = (float)((fabs(dyn[q * 4 + 3]) > thr) ? dyn[q * 4 + 3] : 0.0);
        *(float4*)(C + base + q * 256 + col0) = o4;
    }
}

// ---------------------------------------------------------------------------
extern "C" void kernel_launch(void* const* d_in, const int* in_sizes, int n_in,
                              void* d_out, int out_size, void* d_ws, size_t ws_size,
                              hipStream_t stream)
{
    const float* F   = (const float*)d_in[0];
    const float* wg1 = (const float*)d_in[1];
    const float* bg1 = (const float*)d_in[2];
    const float* wg2 = (const float*)d_in[3];
    const float* bg2 = (const float*)d_in[4];
    // d_in[5..8]: competition calculator — provably dead (win == False always)
    const float* wr1 = (const float*)d_in[9];
    const float* br1 = (const float*)d_in[10];
    const float* wr2 = (const float*)d_in[11];
    const float* br2 = (const float*)d_in[12];
    const float* wm1 = (const float*)d_in[13];
    const float* bm1 = (const float*)d_in[14];
    const float* wm2 = (const float*)d_in[15];
    const float* bm2 = (const float*)d_in[16];

    float* out = (float*)d_out;
    const int M = in_sizes[0] / 1024;                      // 32768

    float*    h1      = (float*)d_ws;                      // 32 MiB
    uint2*    list    = (uint2*)((char*)d_ws + (32u << 20));   // 2 MiB
    unsigned* counter = (unsigned*)((char*)d_ws + (34u << 20));

    hipMemsetAsync(counter, 0, sizeof(unsigned), stream);
    gemm1_f32<<<dim3(M / TM, 256 / TN), 256, 0, stream>>>(F, wg1, bg1, h1, M);
    gemm2_f32<<<dim3(M / TM, 1024 / TN), 256, 0, stream>>>(h1, wg2, bg2, F, out, counter, list, M);
    fix_exact<<<2048, 256, 0, stream>>>(F, wg1, bg1, wg2, bg2, counter, list, out);
    finalize_rows<<<M / 4, 256, 0, stream>>>(out, wr1, br1, wr2, br2, wm1, bm1, wm2, bm2);
}